// Round 1
// baseline (529.932 us; speedup 1.0000x reference)
//
#include <hip/hip_runtime.h>

typedef unsigned short u16;
typedef __attribute__((ext_vector_type(4))) unsigned short u16x4;
typedef __attribute__((ext_vector_type(8))) unsigned short u16x8;
typedef __attribute__((ext_vector_type(8))) short s16x8;
typedef __attribute__((ext_vector_type(4))) float f32x4;

#define BATCH 16384
#define NFEAT 32
#define NVOCAB 50000

__device__ __forceinline__ u16 f2bf(float f) {
    union { float f; unsigned u; } v; v.f = f;
    unsigned u = v.u;
    return (u16)((u + 0x7fffu + ((u >> 16) & 1u)) >> 16);
}
__device__ __forceinline__ float bf2f(u16 h) {
    union { unsigned u; float f; } v; v.u = ((unsigned)h) << 16;
    return v.f;
}

// ---------------------------------------------------------------------------
// Weight prep: fp32 [z][K][N] -> bf16 [z][N][K] (transposed, K-contiguous)
// ---------------------------------------------------------------------------
struct PrepDesc { const float* src; u16* dst; int K; int N; int nz; int zbase; };
struct PrepArgs { PrepDesc d[6]; };

__global__ void prep_weights(PrepArgs args) {
    int z = blockIdx.z;
    int di = 0;
    #pragma unroll
    for (int i = 0; i < 6; i++)
        if (z >= args.d[i].zbase && z < args.d[i].zbase + args.d[i].nz) di = i;
    PrepDesc d = args.d[di];
    int zz = z - d.zbase;
    int k0 = blockIdx.x * 32, n0 = blockIdx.y * 32;
    if (k0 >= d.K || n0 >= d.N) return;
    __shared__ float tile[32][33];
    const float* src = d.src + (long)zz * d.K * d.N;
    u16* dst = d.dst + (long)zz * d.K * d.N;
    int tx = threadIdx.x & 31, ty = threadIdx.x >> 5;
    for (int r = ty; r < 32; r += 8) {
        int k = k0 + r, n = n0 + tx;
        tile[r][tx] = (k < d.K && n < d.N) ? src[(long)k * d.N + n] : 0.f;
    }
    __syncthreads();
    for (int r = ty; r < 32; r += 8) {
        int n = n0 + r, k = k0 + tx;
        if (n < d.N && k < d.K) dst[(long)n * d.K + k] = f2bf(tile[tx][r]);
    }
}

// ---------------------------------------------------------------------------
// Embedding gather: emb fp32 [F][V][16], ids [B][F] -> embed bf16 [B][512]
// ---------------------------------------------------------------------------
__global__ void gather_embed(const int* __restrict__ ids,
                             const float* __restrict__ emb,
                             u16* __restrict__ out) {
    int idx = blockIdx.x * 256 + threadIdx.x;   // B*F*4 threads
    int d4 = idx & 3;
    int f  = (idx >> 2) & 31;
    int b  = idx >> 7;
    int id = ids[b * NFEAT + f];
    const float4* p = (const float4*)(emb + ((long)f * NVOCAB + id) * 16) + d4;
    float4 v = *p;
    u16x4 o;
    o.x = f2bf(v.x); o.y = f2bf(v.y); o.z = f2bf(v.z); o.w = f2bf(v.w);
    *(u16x4*)(out + (long)b * 512 + f * 16 + d4 * 4) = o;
}

// ---------------------------------------------------------------------------
// Generic batched GEMM:  C[z] = act(A[z/a_zdiv] @ Bt[z]^T + bias[z])
// A bf16 [.,M,K] row-major, Bt bf16 [z][N][K] (pre-transposed weights)
// tile 128x128, BK=64, 4 waves of 64x64, mfma 16x16x32 bf16
// ACT: 0 none, 1 relu, 2 sigmoid.  OUT_T: u16 (bf16) or float.
// ---------------------------------------------------------------------------
template<int ACT, typename OUT_T>
__global__ __launch_bounds__(256, 2)
void gemm_bt(const u16* __restrict__ A, const u16* __restrict__ Bt,
             const float* __restrict__ bias, OUT_T* __restrict__ C,
             int M, int N, int K,
             long a_zstride, int a_zdiv, long c_zstride, int c_row_stride) {
    constexpr int LROW = 72;   // 64 + 8 pad (bf16 units) -> 2-way-free banks
    __shared__ u16 sA[128 * LROW];
    __shared__ u16 sB[128 * LROW];
    const int z = blockIdx.z;
    const u16* Ab = A + (long)(z / a_zdiv) * a_zstride;
    const u16* Bb = Bt + (long)z * N * K;
    const int m0 = blockIdx.x * 128;
    const int n0 = blockIdx.y * 128;
    const int tid = threadIdx.x;
    const int lane = tid & 63;
    const int w = tid >> 6;
    const int wm = (w & 1) * 64;
    const int wn = (w >> 1) * 64;
    const int l16 = lane & 15;
    const int q = lane >> 4;

    f32x4 acc[4][4] = {};

    for (int k0 = 0; k0 < K; k0 += 64) {
        u16x8 va[4], vb[4];
        #pragma unroll
        for (int i = 0; i < 4; i++) {
            int c = tid + i * 256;
            int row = c >> 3;
            int col = (c & 7) * 8;
            va[i] = *(const u16x8*)(Ab + (long)(m0 + row) * K + k0 + col);
            int nrow = n0 + row;
            if (nrow < N) vb[i] = *(const u16x8*)(Bb + (long)nrow * K + k0 + col);
            else          vb[i] = (u16x8)0;
        }
        __syncthreads();   // previous iter's LDS reads done
        #pragma unroll
        for (int i = 0; i < 4; i++) {
            int c = tid + i * 256;
            int row = c >> 3;
            int col = (c & 7) * 8;
            *(u16x8*)(&sA[row * LROW + col]) = va[i];
            *(u16x8*)(&sB[row * LROW + col]) = vb[i];
        }
        __syncthreads();
        #pragma unroll
        for (int kk = 0; kk < 2; kk++) {
            s16x8 af[4], bfr[4];
            #pragma unroll
            for (int i = 0; i < 4; i++)
                af[i] = *(const s16x8*)(&sA[(wm + i * 16 + l16) * LROW + kk * 32 + q * 8]);
            #pragma unroll
            for (int i = 0; i < 4; i++)
                bfr[i] = *(const s16x8*)(&sB[(wn + i * 16 + l16) * LROW + kk * 32 + q * 8]);
            #pragma unroll
            for (int mt = 0; mt < 4; mt++)
                #pragma unroll
                for (int nt = 0; nt < 4; nt++)
                    acc[mt][nt] = __builtin_amdgcn_mfma_f32_16x16x32_bf16(
                        af[mt], bfr[nt], acc[mt][nt], 0, 0, 0);
        }
    }

    const float* bb = bias + (long)z * N;
    OUT_T* Cp = C + (long)z * c_zstride;
    #pragma unroll
    for (int nt = 0; nt < 4; nt++) {
        int gcol = n0 + wn + nt * 16 + l16;
        if (gcol >= N) continue;
        float bv = bb[gcol];
        #pragma unroll
        for (int mt = 0; mt < 4; mt++) {
            int grow = m0 + wm + mt * 16 + q * 4;
            #pragma unroll
            for (int r = 0; r < 4; r++) {
                float v = acc[mt][nt][r] + bv;
                if (ACT == 1) v = fmaxf(v, 0.f);
                else if (ACT == 2) v = 1.f / (1.f + __expf(-v));
                if constexpr (sizeof(OUT_T) == 2)
                    Cp[(long)(grow + r) * c_row_stride + gcol] = f2bf(v);
                else
                    Cp[(long)(grow + r) * c_row_stride + gcol] = v;
            }
        }
    }
}

// ---------------------------------------------------------------------------
// Level-1 gates + combine: x1[3][B][256] from embed (gates) and out1[6][B][256]
// ---------------------------------------------------------------------------
__global__ void gate_combine1(const u16* __restrict__ embed,
                              const u16* __restrict__ out1,
                              const float* __restrict__ g1Ws, const float* __restrict__ g1bs,
                              const float* __restrict__ gWsh, const float* __restrict__ gbsh,
                              u16* __restrict__ x1) {
    int b = blockIdx.x;
    __shared__ float sgw[14];   // 0..3 t0, 4..7 t1, 8..13 shared
    int tid = threadIdx.x, w = tid >> 6, lane = tid & 63;
    if (w < 3) {
        int ng = (w == 2) ? 6 : 4;
        const float* W = (w == 2) ? gWsh : (g1Ws + w * 512 * 4);
        const u16* xr = embed + (long)b * 512;
        float lg[6] = {0, 0, 0, 0, 0, 0};
        for (int e = lane; e < 512; e += 64) {
            float xv = bf2f(xr[e]);
            #pragma unroll
            for (int g = 0; g < 6; g++)
                if (g < ng) lg[g] += xv * W[e * ng + g];
        }
        #pragma unroll
        for (int g = 0; g < 6; g++) {
            float v = lg[g];
            for (int off = 32; off > 0; off >>= 1) v += __shfl_xor(v, off);
            lg[g] = v;
        }
        if (lane == 0) {
            const float* bs = (w == 2) ? gbsh : (g1bs + w * 4);
            float mx = -1e30f;
            for (int g = 0; g < ng; g++) { lg[g] += bs[g]; mx = fmaxf(mx, lg[g]); }
            float s = 0.f, ex[6];
            for (int g = 0; g < ng; g++) { ex[g] = __expf(lg[g] - mx); s += ex[g]; }
            int base = (w == 2) ? 8 : w * 4;
            for (int g = 0; g < ng; g++) sgw[base + g] = ex[g] / s;
        }
    }
    __syncthreads();
    int j = tid;   // 0..255
    const u16* ob = out1 + (long)b * 256 + j;
    float o[6];
    #pragma unroll
    for (int k = 0; k < 6; k++) o[k] = bf2f(ob[(long)k * BATCH * 256]);
    float v0 = sgw[0] * o[0] + sgw[1] * o[1] + sgw[2] * o[4] + sgw[3] * o[5];
    float v1 = sgw[4] * o[2] + sgw[5] * o[3] + sgw[6] * o[4] + sgw[7] * o[5];
    float v2 = 0.f;
    #pragma unroll
    for (int k = 0; k < 6; k++) v2 += sgw[8 + k] * o[k];
    x1[((long)0 * BATCH + b) * 256 + j] = f2bf(v0);
    x1[((long)1 * BATCH + b) * 256 + j] = f2bf(v1);
    x1[((long)2 * BATCH + b) * 256 + j] = f2bf(v2);
}

// ---------------------------------------------------------------------------
// Level-2 gates + combine: x2[2][B][256] from x1 (gates) and out2[6][B][256]
// ---------------------------------------------------------------------------
__global__ void gate_combine2(const u16* __restrict__ x1,
                              const u16* __restrict__ out2,
                              const float* __restrict__ g2Ws, const float* __restrict__ g2bs,
                              u16* __restrict__ x2) {
    int b = blockIdx.x;
    __shared__ float sgw[8];
    int tid = threadIdx.x, w = tid >> 6, lane = tid & 63;
    if (w < 2) {
        const float* W = g2Ws + w * 256 * 4;
        const u16* xr = x1 + ((long)w * BATCH + b) * 256;
        float lg[4] = {0, 0, 0, 0};
        for (int e = lane; e < 256; e += 64) {
            float xv = bf2f(xr[e]);
            #pragma unroll
            for (int g = 0; g < 4; g++) lg[g] += xv * W[e * 4 + g];
        }
        #pragma unroll
        for (int g = 0; g < 4; g++) {
            float v = lg[g];
            for (int off = 32; off > 0; off >>= 1) v += __shfl_xor(v, off);
            lg[g] = v;
        }
        if (lane == 0) {
            float mx = -1e30f;
            for (int g = 0; g < 4; g++) { lg[g] += g2bs[w * 4 + g]; mx = fmaxf(mx, lg[g]); }
            float s = 0.f, ex[4];
            for (int g = 0; g < 4; g++) { ex[g] = __expf(lg[g] - mx); s += ex[g]; }
            for (int g = 0; g < 4; g++) sgw[w * 4 + g] = ex[g] / s;
        }
    }
    __syncthreads();
    int j = tid;
    const u16* ob = out2 + (long)b * 256 + j;
    float o[6];
    #pragma unroll
    for (int k = 0; k < 6; k++) o[k] = bf2f(ob[(long)k * BATCH * 256]);
    float v0 = sgw[0] * o[0] + sgw[1] * o[1] + sgw[2] * o[4] + sgw[3] * o[5];
    float v1 = sgw[4] * o[2] + sgw[5] * o[3] + sgw[6] * o[4] + sgw[7] * o[5];
    x2[((long)0 * BATCH + b) * 256 + j] = f2bf(v0);
    x2[((long)1 * BATCH + b) * 256 + j] = f2bf(v1);
}

// ---------------------------------------------------------------------------
extern "C" void kernel_launch(void* const* d_in, const int* in_sizes, int n_in,
                              void* d_out, int out_size, void* d_ws, size_t ws_size,
                              hipStream_t stream) {
    const int*   x_ids = (const int*)  d_in[0];
    const float* emb   = (const float*)d_in[1];
    const float* e1W1  = (const float*)d_in[2];
    const float* e1b1  = (const float*)d_in[3];
    const float* e1W2  = (const float*)d_in[4];
    const float* e1b2  = (const float*)d_in[5];
    const float* g1Ws  = (const float*)d_in[6];
    const float* g1bs  = (const float*)d_in[7];
    const float* g1Wsh = (const float*)d_in[8];
    const float* g1bsh = (const float*)d_in[9];
    const float* e2W1  = (const float*)d_in[10];
    const float* e2b1  = (const float*)d_in[11];
    const float* e2W2  = (const float*)d_in[12];
    const float* e2b2  = (const float*)d_in[13];
    const float* g2Ws  = (const float*)d_in[14];
    const float* g2bs  = (const float*)d_in[15];
    const float* twW1  = (const float*)d_in[16];
    const float* twb1  = (const float*)d_in[17];
    const float* twW2  = (const float*)d_in[18];
    const float* twb2  = (const float*)d_in[19];
    float* out = (float*)d_out;

    char* ws = (char*)d_ws;
    // workspace layout (bytes); total ~226 MB
    u16* embed   = (u16*)(ws + 0);                       // [B,512]        16.78 MB
    u16* wt_e1W1 = (u16*)(ws + 16777216);                // [6,512,512]     3.15 MB
    u16* wt_e1W2 = (u16*)(ws + 19922944);                // [6,256,512]     1.57 MB
    u16* wt_e2W1 = (u16*)(ws + 21495808);                // [6,512,256]     1.57 MB
    u16* wt_e2W2 = (u16*)(ws + 23068672);                // [6,256,512]     1.57 MB
    u16* wt_twW1 = (u16*)(ws + 24641536);                // [2,128,256]     0.13 MB
    u16* wt_twW2 = (u16*)(ws + 24772608);                // [2,64,128]      0.03 MB
    u16* h_buf   = (u16*)(ws + 24805376);                // [6,B,512] h1/h2 100.66 MB
    u16* o_buf   = (u16*)(ws + 125468672);               // [6,B,256] out1/out2 50.33 MB
    u16* x1      = (u16*)(ws + 175800320);               // [3,B,256]      25.17 MB
    u16* x2      = (u16*)(ws + 200966144);               // [2,B,256]      16.78 MB
    u16* th      = (u16*)(ws + 217743360);               // [2,B,128]       8.39 MB

    // 1) weight transpose+cast
    PrepArgs pa;
    pa.d[0] = { e1W1, wt_e1W1, 512, 512, 6,  0 };
    pa.d[1] = { e1W2, wt_e1W2, 512, 256, 6,  6 };
    pa.d[2] = { e2W1, wt_e2W1, 256, 512, 6, 12 };
    pa.d[3] = { e2W2, wt_e2W2, 512, 256, 6, 18 };
    pa.d[4] = { twW1, wt_twW1, 256, 128, 2, 24 };
    pa.d[5] = { twW2, wt_twW2, 128,  64, 2, 26 };
    prep_weights<<<dim3(16, 16, 28), 256, 0, stream>>>(pa);

    // 2) embedding gather
    gather_embed<<<dim3(BATCH * NFEAT * 4 / 256), 256, 0, stream>>>(x_ids, emb, embed);

    // 3) level-1 experts: h1 = relu(embed @ W1 + b1), all 6 experts share A
    gemm_bt<1, u16><<<dim3(128, 4, 6), 256, 0, stream>>>(
        embed, wt_e1W1, e1b1, h_buf, BATCH, 512, 512,
        0L, 1, (long)BATCH * 512, 512);
    gemm_bt<1, u16><<<dim3(128, 2, 6), 256, 0, stream>>>(
        h_buf, wt_e1W2, e1b2, o_buf, BATCH, 256, 512,
        (long)BATCH * 512, 1, (long)BATCH * 256, 256);

    // 4) level-1 gates + combine -> x1[3]
    gate_combine1<<<dim3(BATCH), 256, 0, stream>>>(embed, o_buf, g1Ws, g1bs, g1Wsh, g1bsh, x1);

    // 5) level-2 experts: A per expert = x1[e/2]
    gemm_bt<1, u16><<<dim3(128, 4, 6), 256, 0, stream>>>(
        x1, wt_e2W1, e2b1, h_buf, BATCH, 512, 256,
        (long)BATCH * 256, 2, (long)BATCH * 512, 512);
    gemm_bt<1, u16><<<dim3(128, 2, 6), 256, 0, stream>>>(
        h_buf, wt_e2W2, e2b2, o_buf, BATCH, 256, 512,
        (long)BATCH * 512, 1, (long)BATCH * 256, 256);

    // 6) level-2 gates + combine -> x2[2]
    gate_combine2<<<dim3(BATCH), 256, 0, stream>>>(x1, o_buf, g2Ws, g2bs, x2);

    // 7) towers
    gemm_bt<1, u16><<<dim3(128, 1, 2), 256, 0, stream>>>(
        x2, wt_twW1, twb1, th, BATCH, 128, 256,
        (long)BATCH * 256, 1, (long)BATCH * 128, 128);
    gemm_bt<2, float><<<dim3(128, 1, 2), 256, 0, stream>>>(
        th, wt_twW2, twb2, out, BATCH, 64, 128,
        (long)BATCH * 128, 1, 64L, 128);
}